// Round 11
// baseline (448.998 us; speedup 1.0000x reference)
//
#include <hip/hip_runtime.h>
#include <hip/hip_bf16.h>

#define NN 50000
#define NE 800000

typedef short short8 __attribute__((ext_vector_type(8)));
typedef float f32x4 __attribute__((ext_vector_type(4)));
typedef unsigned short ushort_t;

// ---- truncation-based bf16 hi/lo split helpers ----
static __device__ __forceinline__ unsigned bits(float f) { return __float_as_uint(f); }
static __device__ __forceinline__ float hi_f(float v) {
  return __uint_as_float(bits(v) & 0xFFFF0000u);
}
static __device__ __forceinline__ ushort_t hi_u(float v) { return (ushort_t)(bits(v) >> 16); }
static __device__ __forceinline__ unsigned pack_hi(float v0, float v1) {
  return (bits(v0) >> 16) | (bits(v1) & 0xFFFF0000u);
}
static __device__ __forceinline__ unsigned pack_lo(float v0, float v1) {
  float l0 = v0 - hi_f(v0), l1 = v1 - hi_f(v1);
  return (bits(l0) >> 16) | (bits(l1) & 0xFFFF0000u);
}

#define MFMA(a, b, c) __builtin_amdgcn_mfma_f32_16x16x32_bf16(a, b, c, 0, 0, 0)

// ---------------- kA: weight-pack (t<4096) + x hi/lo split (t<800000) + CSR offsets.
__global__ __launch_bounds__(256) void kA_pack_off(
    const float* __restrict__ x,
    const float* __restrict__ Wn, const float* __restrict__ Wc,
    const float* __restrict__ Wu, const float* __restrict__ base_w,
    const float* __restrict__ spline_w, const float* __restrict__ scaler,
    const int* __restrict__ seg,
    ushort_t* __restrict__ xh, ushort_t* __restrict__ xl,
    ushort_t* __restrict__ p1h, ushort_t* __restrict__ p1l,
    ushort_t* __restrict__ p2h, ushort_t* __restrict__ p2l,
    ushort_t* __restrict__ p3h, ushort_t* __restrict__ p3l,
    int* __restrict__ off) {
  int t = blockIdx.x * 256 + threadIdx.x;
  if (t < 4096) {
    int l = t & 63, lm = l & 15, lk = l >> 4;
    if (t < 2048) {
      int nt = t >> 8, ks = (t >> 6) & 3;
      int h = nt * 16 + lm;
#pragma unroll
      for (int j = 0; j < 8; ++j) {
        int f = ks * 32 + lk * 8 + j;
        float v = (f < 64) ? Wn[h * 64 + f] : Wc[h * 64 + (f - 64)];
        p1h[t * 8 + j] = hi_u(v);
        p1l[t * 8 + j] = (ushort_t)(bits(v - hi_f(v)) >> 16);
      }
    }
    if (t < 1024) {
      int nt = t >> 8, ks = (t >> 6) & 3;
      int o = nt * 16 + lm;
#pragma unroll
      for (int j = 0; j < 8; ++j) {
        int hh = ks * 32 + lk * 8 + j;
        float v = Wu[o * 128 + hh];
        p2h[t * 8 + j] = hi_u(v);
        p2l[t * 8 + j] = (ushort_t)(bits(v - hi_f(v)) >> 16);
      }
    }
    if (t < 3072) {
      int nt = t / 768, ks = (t >> 6) % 12;
      int o = nt * 16 + lm;
#pragma unroll
      for (int j = 0; j < 8; ++j) {
        int k = ks * 32 + lk * 8 + j;
        int i = k / 6, c = k % 6;
        float v = (c == 0) ? base_w[o * 64 + i]
                           : spline_w[(o * 64 + i) * 5 + (c - 1)] * scaler[o * 64 + i];
        p3h[t * 8 + j] = hi_u(v);
        p3l[t * 8 + j] = (ushort_t)(bits(v - hi_f(v)) >> 16);
      }
    }
  }
  if (t < 800000) {
    float4 xv = ((const float4*)x)[t];
    uint2 hp, lp;
    hp.x = pack_hi(xv.x, xv.y);
    hp.y = pack_hi(xv.z, xv.w);
    lp.x = pack_lo(xv.x, xv.y);
    lp.y = pack_lo(xv.z, xv.w);
    *(uint2*)&xh[(size_t)t * 4] = hp;
    *(uint2*)&xl[(size_t)t * 4] = lp;
  }
  int e = t;
  if (e < NE) {
    int s1 = seg[e];
    if (e == 0) {
      for (int n = 0; n <= s1; ++n) off[n] = 0;
    } else {
      int s0 = seg[e - 1];
      for (int n = s0 + 1; n <= s1; ++n) off[n] = e;
    }
    if (e == NE - 1) {
      for (int n = s1 + 1; n <= NN; ++n) off[n] = NE;
    }
  }
}

// ---------------- k1: per-node edge aggregation; writes Sp as bf16 hi/lo.
__global__ __launch_bounds__(256) void k1_edge_agg(
    const float* __restrict__ contexts, const float* __restrict__ attn,
    const int* __restrict__ off, ushort_t* __restrict__ Sph,
    ushort_t* __restrict__ Spl, float* __restrict__ aprime,
    float* __restrict__ degw) {
  int n = blockIdx.x * 4 + (threadIdx.x >> 6);
  int lane = threadIdx.x & 63;
  if (n >= NN) return;
  int s = off[n];
  int e_end = off[n + 1];
  int deg_i = e_end - s;

  int sub = lane >> 4;
  int fq = lane & 15;
  const float4* ctx4 = (const float4*)contexts;

  float4 S = make_float4(0.f, 0.f, 0.f, 0.f);
  float A = 0.f;
  if (deg_i > 0) {
    int last = e_end - 1;
    for (int e0 = s; e0 < e_end; e0 += 16) {
      float a[4];
      float4 c[4];
#pragma unroll
      for (int u = 0; u < 4; ++u) {
        int eu = e0 + 4 * u + sub;
        a[u] = (eu < e_end) ? attn[eu] : 0.f;
        c[u] = ctx4[(size_t)min(eu, last) * 16 + fq];
      }
#pragma unroll
      for (int u = 0; u < 4; ++u) {
        S.x += a[u] * c[u].x;
        S.y += a[u] * c[u].y;
        S.z += a[u] * c[u].z;
        S.w += a[u] * c[u].w;
        A += a[u];
      }
    }
  }
#pragma unroll
  for (int m = 16; m <= 32; m <<= 1) {
    S.x += __shfl_xor(S.x, m);
    S.y += __shfl_xor(S.y, m);
    S.z += __shfl_xor(S.z, m);
    S.w += __shfl_xor(S.w, m);
    A += __shfl_xor(A, m);
  }
  float deg = (float)deg_i;
  float inv = 1.f / fmaxf(deg, 1.f);
  if (lane < 16) {
    float ox = S.x * inv, oy = S.y * inv, oz = S.z * inv, ow = S.w * inv;
    uint2 hp, lp;
    hp.x = pack_hi(ox, oy);
    hp.y = pack_hi(oz, ow);
    lp.x = pack_lo(ox, oy);
    lp.y = pack_lo(oz, ow);
    *(uint2*)&Sph[(size_t)n * 64 + lane * 4] = hp;
    *(uint2*)&Spl[(size_t)n * 64 + lane * 4] = lp;
  }
  if (lane == 0) { aprime[n] = A * inv; degw[n] = deg; }
}

// ---------------- k234t: phase-ablation template of the fused MFMA pipeline.
// PHASE 0: staging only.  PHASE 1: +GEMM1/T.  PHASE 2: +GEMM2+transform+V-write.
// PHASE 3: full (writes out).  REPN: idempotent repeats for rocprof visibility.
template <int PHASE, int REPN>
__global__ __launch_bounds__(256, 3) void k234t(
    const ushort_t* __restrict__ xh, const ushort_t* __restrict__ xl,
    const ushort_t* __restrict__ Sph, const ushort_t* __restrict__ Spl,
    const float* __restrict__ x,
    const float* __restrict__ aprime, const float* __restrict__ degw,
    const float* __restrict__ bn, const float* __restrict__ bc,
    const float* __restrict__ bu,
    const ushort_t* __restrict__ p1h, const ushort_t* __restrict__ p1l,
    const ushort_t* __restrict__ p2h, const ushort_t* __restrict__ p2l,
    const ushort_t* __restrict__ p3h, const ushort_t* __restrict__ p3l,
    const float* __restrict__ gridp, float* __restrict__ out,
    float* __restrict__ scr) {
  __shared__ __align__(16) unsigned char arena[49152];
  __shared__ float ap[64], degl[64];
  ushort_t* Uh = (ushort_t*)arena;             // [64][128] swizzled
  ushort_t* Ul = (ushort_t*)(arena + 16384);   // [64][128] swizzled
  ushort_t* Th = (ushort_t*)(arena + 32768);   // [64][128] swizzled
  ushort_t* Vh = (ushort_t*)arena;             // [32][392], overlays Uh/Ul

  int tid = threadIdx.x;
  int n0 = blockIdx.x * 64;

  float g[8];
#pragma unroll
  for (int j = 0; j < 8; ++j) g[j] = gridp[j];
  float r1[7], r2[6];
#pragma unroll
  for (int j = 0; j < 7; ++j) r1[j] = 1.f / (g[j + 1] - g[j]);
#pragma unroll
  for (int j = 0; j < 6; ++j) r2[j] = 1.f / (g[j + 2] - g[j]);

  int w = tid >> 6, l = tid & 63;
  int lm = l & 15, lk = l >> 4;
  const short8* P1h = (const short8*)p1h;
  const short8* P1l = (const short8*)p1l;
  const short8* P2h = (const short8*)p2h;
  const short8* P2l = (const short8*)p2l;
  const short8* P3h = (const short8*)p3h;
  const short8* P3l = (const short8*)p3l;
  float buv = bu[w * 16 + lm];
  int swzA = (lm & 7) << 3;

#pragma unroll 1
  for (int rep = 0; rep < REPN; ++rep) {
    // ---- stage [xh|Sph] and [xl|Spl] tiles: pure 16B copies, swizzled dest
    {
      const uint4* xh4 = (const uint4*)xh;
      const uint4* xl4 = (const uint4*)xl;
      const uint4* Sh4 = (const uint4*)Sph;
      const uint4* Sl4 = (const uint4*)Spl;
      for (int q = tid; q < 2048; q += 256) {
        int arr = q >> 10;
        int c = q & 1023;
        int row = c >> 4, slot = c & 15;
        int n = n0 + row;
        uint4 v = make_uint4(0u, 0u, 0u, 0u);
        if (n < NN) {
          if (arr == 0) v = (slot < 8) ? xh4[(size_t)n * 8 + slot] : Sh4[(size_t)n * 8 + (slot & 7)];
          else          v = (slot < 8) ? xl4[(size_t)n * 8 + slot] : Sl4[(size_t)n * 8 + (slot & 7)];
        }
        int idx = (row * 128 + slot * 8) ^ ((row & 7) << 3);
        ushort_t* dst = arr ? Ul : Uh;
        *(uint4*)&dst[idx] = v;
      }
    }
    if (tid < 64) {
      int n = n0 + tid;
      ap[tid] = (n < NN) ? aprime[n] : 0.f;
      degl[tid] = (n < NN) ? degw[n] : 1.f;
    }
    __syncthreads();  // A

    if constexpr (PHASE == 0) {
      // keep staging live: checksum of LDS
      float s = (float)Uh[(tid * 8) & 8191] + (float)Ul[(tid * 8 + 3) & 8191] + ap[tid & 63];
      scr[blockIdx.x * 256 + tid] = s;
      __syncthreads();
      continue;
    }

    // ---- GEMM1 (3-term, N-split): wave w -> h-tiles {2w,2w+1} sequentially. K=128.
#pragma unroll
    for (int q2 = 0; q2 < 2; ++q2) {
      int ht = 2 * w + q2;
      f32x4 acc[4];
#pragma unroll
      for (int mt = 0; mt < 4; ++mt) acc[mt] = (f32x4){0.f, 0.f, 0.f, 0.f};
#pragma unroll 2
      for (int ks = 0; ks < 4; ++ks) {
        short8 bh = P1h[(ht * 4 + ks) * 64 + l];
        short8 bl = P1l[(ht * 4 + ks) * 64 + l];
#pragma unroll
        for (int mt = 0; mt < 4; ++mt) {
          int ai = ((mt * 16 + lm) * 128 + ks * 32 + lk * 8) ^ swzA;
          short8 ah = *(const short8*)&Uh[ai];
          short8 al = *(const short8*)&Ul[ai];
          acc[mt] = MFMA(ah, bh, acc[mt]);
          acc[mt] = MFMA(al, bh, acc[mt]);
          acc[mt] = MFMA(ah, bl, acc[mt]);
        }
      }
      int h = ht * 16 + lm;
      float bnv = bn[h], bcv = bc[h];
#pragma unroll
      for (int mt = 0; mt < 4; ++mt) {
#pragma unroll
        for (int r = 0; r < 4; ++r) {
          int node = mt * 16 + lk * 4 + r;
          float t = acc[mt][r] + bnv + ap[node] * bcv;
          Th[(node * 128 + h) ^ ((node & 7) << 3)] = hi_u(t);
        }
      }
    }
    __syncthreads();  // B

    if constexpr (PHASE == 1) {
      scr[blockIdx.x * 256 + tid] = (float)Th[(tid * 8) & 8191];
      __syncthreads();
      continue;
    }

    // ---- GEMM2 (2-term): wave w -> o-tile w. K=128.
    f32x4 acc2[4];
#pragma unroll
    for (int mt = 0; mt < 4; ++mt) acc2[mt] = (f32x4){0.f, 0.f, 0.f, 0.f};
#pragma unroll 2
    for (int ks = 0; ks < 4; ++ks) {
      short8 bh = P2h[(w * 4 + ks) * 64 + l];
      short8 bl = P2l[(w * 4 + ks) * 64 + l];
#pragma unroll
      for (int mt = 0; mt < 4; ++mt) {
        int ai = ((mt * 16 + lm) * 128 + ks * 32 + lk * 8) ^ swzA;
        short8 ah = *(const short8*)&Th[ai];
        acc2[mt] = MFMA(ah, bh, acc2[mt]);
        acc2[mt] = MFMA(ah, bl, acc2[mt]);
      }
    }

    if constexpr (PHASE == 2) {
      // transform + V-write both halves (no KAN GEMM): same thread->addr map each half
#pragma unroll
      for (int mt = 0; mt < 4; ++mt) {
#pragma unroll
        for (int r = 0; r < 4; ++r) {
          float xv = acc2[mt][r] + buv;
          float sil = xv / (1.f + __expf(-xv));
          float b0[7], b1[6], b2[5];
#pragma unroll
          for (int q = 0; q < 7; ++q) b0[q] = (xv >= g[q] && xv < g[q + 1]) ? 1.f : 0.f;
#pragma unroll
          for (int q = 0; q < 6; ++q)
            b1[q] = (xv - g[q]) * r1[q] * b0[q] + (g[q + 2] - xv) * r1[q + 1] * b0[q + 1];
#pragma unroll
          for (int q = 0; q < 5; ++q)
            b2[q] = (xv - g[q]) * r2[q] * b1[q] + (g[q + 3] - xv) * r2[q + 1] * b1[q + 1];
          int ln = (mt & 1) * 16 + lk * 4 + r;
          int base = ln * 392 + (w * 16 + lm) * 6;
          *(unsigned*)&Vh[base + 0] = pack_hi(sil, b2[0]);
          *(unsigned*)&Vh[base + 2] = pack_hi(b2[1], b2[2]);
          *(unsigned*)&Vh[base + 4] = pack_hi(b2[3], b2[4]);
        }
      }
      __syncthreads();
      scr[blockIdx.x * 256 + tid] = (float)Vh[(tid * 8) & 8191];
      __syncthreads();
      continue;
    }

    // ---- PHASE 3: full KAN, two 32-node halves
#pragma unroll
    for (int half = 0; half < 2; ++half) {
#pragma unroll
      for (int ms = 0; ms < 2; ++ms) {
        int mt = half * 2 + ms;
#pragma unroll
        for (int r = 0; r < 4; ++r) {
          float xv = acc2[mt][r] + buv;
          float sil = xv / (1.f + __expf(-xv));
          float b0[7], b1[6], b2[5];
#pragma unroll
          for (int q = 0; q < 7; ++q) b0[q] = (xv >= g[q] && xv < g[q + 1]) ? 1.f : 0.f;
#pragma unroll
          for (int q = 0; q < 6; ++q)
            b1[q] = (xv - g[q]) * r1[q] * b0[q] + (g[q + 2] - xv) * r1[q + 1] * b0[q + 1];
#pragma unroll
          for (int q = 0; q < 5; ++q)
            b2[q] = (xv - g[q]) * r2[q] * b1[q] + (g[q + 3] - xv) * r2[q + 1] * b1[q + 1];
          int ln = ms * 16 + lk * 4 + r;
          int base = ln * 392 + (w * 16 + lm) * 6;
          *(unsigned*)&Vh[base + 0] = pack_hi(sil, b2[0]);
          *(unsigned*)&Vh[base + 2] = pack_hi(b2[1], b2[2]);
          *(unsigned*)&Vh[base + 4] = pack_hi(b2[3], b2[4]);
        }
      }
      __syncthreads();  // V ready

      f32x4 accK[2];
      accK[0] = (f32x4){0.f, 0.f, 0.f, 0.f};
      accK[1] = (f32x4){0.f, 0.f, 0.f, 0.f};
#pragma unroll 3
      for (int ks = 0; ks < 12; ++ks) {
        short8 bh = P3h[(w * 12 + ks) * 64 + l];
        short8 bl = P3l[(w * 12 + ks) * 64 + l];
#pragma unroll
        for (int s = 0; s < 2; ++s) {
          short8 ah = *(const short8*)&Vh[(s * 16 + lm) * 392 + ks * 32 + lk * 8];
          accK[s] = MFMA(ah, bh, accK[s]);
          accK[s] = MFMA(ah, bl, accK[s]);
        }
      }
      __syncthreads();  // V reads done before half1 (or next rep) overwrites

#pragma unroll
      for (int s = 0; s < 2; ++s) {
        int o = w * 16 + lm;
#pragma unroll
        for (int r = 0; r < 4; ++r) {
          int node = half * 32 + s * 16 + lk * 4 + r;
          int n = n0 + node;
          if (n < NN) {
            float val = accK[s][r];
            if (degl[node] <= 0.f) val = x[(size_t)n * 64 + o];
            out[(size_t)n * 64 + o] = val;
          }
        }
      }
    }
  }
}

extern "C" void kernel_launch(void* const* d_in, const int* in_sizes, int n_in,
                              void* d_out, int out_size, void* d_ws, size_t ws_size,
                              hipStream_t stream) {
  const float* x        = (const float*)d_in[0];
  const float* contexts = (const float*)d_in[1];
  const float* attn     = (const float*)d_in[2];
  const int*   seg      = (const int*)d_in[3];
  const float* Wn       = (const float*)d_in[4];
  const float* bn       = (const float*)d_in[5];
  const float* Wc       = (const float*)d_in[6];
  const float* bc       = (const float*)d_in[7];
  const float* Wu       = (const float*)d_in[8];
  const float* bu       = (const float*)d_in[9];
  const float* base_w   = (const float*)d_in[10];
  const float* spline_w = (const float*)d_in[11];
  const float* scaler   = (const float*)d_in[12];
  const float* gridp    = (const float*)d_in[13];
  float* out = (float*)d_out;

  ushort_t* us  = (ushort_t*)d_ws;
  ushort_t* Sph = us;                    // 3,200,000
  ushort_t* Spl = Sph + 3200000;         // 3,200,000
  ushort_t* xh  = Spl + 3200000;         // 3,200,000
  ushort_t* xl  = xh + 3200000;          // 3,200,000
  ushort_t* p1h = xl + 3200000;          // 16384
  ushort_t* p1l = p1h + 16384;
  ushort_t* p2h = p1l + 16384;           // 8192
  ushort_t* p2l = p2h + 8192;
  ushort_t* p3h = p2l + 8192;            // 24576
  ushort_t* p3l = p3h + 24576;
  float* aprime = (float*)(p3l + 24576); // 50,000
  float* degw   = aprime + 50000;        // 50,000
  int*   off    = (int*)(degw + 50000);  // 50,001
  float* scr    = (float*)(off + 50002); // 782*256 probe scratch

  kA_pack_off<<<3125, 256, 0, stream>>>(x, Wn, Wc, Wu, base_w, spline_w, scaler, seg,
                                        xh, xl, p1h, p1l, p2h, p2l, p3h, p3l, off);
  k1_edge_agg<<<12500, 256, 0, stream>>>(contexts, attn, off, Sph, Spl, aprime, degw);
  // ---- ablation probes (write scratch only; REP-amplified for rocprof visibility)
  k234t<0, 24><<<782, 256, 0, stream>>>(xh, xl, Sph, Spl, x, aprime, degw, bn, bc, bu,
                                        p1h, p1l, p2h, p2l, p3h, p3l, gridp, out, scr);
  k234t<1, 8><<<782, 256, 0, stream>>>(xh, xl, Sph, Spl, x, aprime, degw, bn, bc, bu,
                                       p1h, p1l, p2h, p2l, p3h, p3l, gridp, out, scr);
  k234t<2, 8><<<782, 256, 0, stream>>>(xh, xl, Sph, Spl, x, aprime, degw, bn, bc, bu,
                                       p1h, p1l, p2h, p2l, p3h, p3l, gridp, out, scr);
  // ---- real output (REP=3: also serves as the full-pipeline probe)
  k234t<3, 3><<<782, 256, 0, stream>>>(xh, xl, Sph, Spl, x, aprime, degw, bn, bc, bu,
                                       p1h, p1l, p2h, p2l, p3h, p3l, gridp, out, scr);
}

// Round 12
// 73.148 us; speedup vs baseline: 6.1382x; 6.1382x over previous
//
#include <hip/hip_runtime.h>
#include <hip/hip_bf16.h>

#define NN 50000
#define NE 800000

typedef short short8 __attribute__((ext_vector_type(8)));
typedef float f32x4 __attribute__((ext_vector_type(4)));
typedef unsigned short ushort_t;

// ---- truncation-based bf16 hi/lo split helpers ----
static __device__ __forceinline__ unsigned bits(float f) { return __float_as_uint(f); }
static __device__ __forceinline__ float hi_f(float v) {
  return __uint_as_float(bits(v) & 0xFFFF0000u);
}
static __device__ __forceinline__ ushort_t hi_u(float v) { return (ushort_t)(bits(v) >> 16); }
static __device__ __forceinline__ unsigned pack_hi(float v0, float v1) {
  return (bits(v0) >> 16) | (bits(v1) & 0xFFFF0000u);
}
static __device__ __forceinline__ unsigned pack_lo(float v0, float v1) {
  float l0 = v0 - hi_f(v0), l1 = v1 - hi_f(v1);
  return (bits(l0) >> 16) | (bits(l1) & 0xFFFF0000u);
}

#define MFMA(a, b, c) __builtin_amdgcn_mfma_f32_16x16x32_bf16(a, b, c, 0, 0, 0)

// ---------------- kA: weight-pack hi-only (t < 4096) + CSR offsets (all threads).
// B-frag for W[N][K]: P[((nt*KS+ks)*64+l)*8+j] = W[nt*16+(l&15)][ks*32+8*(l>>4)+j]
__global__ __launch_bounds__(256) void kA_pack_off(
    const float* __restrict__ Wn, const float* __restrict__ Wc,
    const float* __restrict__ Wu, const float* __restrict__ base_w,
    const float* __restrict__ spline_w, const float* __restrict__ scaler,
    const int* __restrict__ seg,
    ushort_t* __restrict__ p1h, ushort_t* __restrict__ p2h,
    ushort_t* __restrict__ p3h, int* __restrict__ off) {
  int t = blockIdx.x * 256 + threadIdx.x;
  if (t < 4096) {
    int l = t & 63, lm = l & 15, lk = l >> 4;
    if (t < 2048) {
      int nt = t >> 8, ks = (t >> 6) & 3;
      int h = nt * 16 + lm;
#pragma unroll
      for (int j = 0; j < 8; ++j) {
        int f = ks * 32 + lk * 8 + j;
        float v = (f < 64) ? Wn[h * 64 + f] : Wc[h * 64 + (f - 64)];
        p1h[t * 8 + j] = hi_u(v);
      }
    }
    if (t < 1024) {
      int nt = t >> 8, ks = (t >> 6) & 3;
      int o = nt * 16 + lm;
#pragma unroll
      for (int j = 0; j < 8; ++j) {
        int hh = ks * 32 + lk * 8 + j;
        p2h[t * 8 + j] = hi_u(Wu[o * 128 + hh]);
      }
    }
    if (t < 3072) {
      int nt = t / 768, ks = (t >> 6) % 12;
      int o = nt * 16 + lm;
#pragma unroll
      for (int j = 0; j < 8; ++j) {
        int k = ks * 32 + lk * 8 + j;
        int i = k / 6, c = k % 6;
        float v = (c == 0) ? base_w[o * 64 + i]
                           : spline_w[(o * 64 + i) * 5 + (c - 1)] * scaler[o * 64 + i];
        p3h[t * 8 + j] = hi_u(v);
      }
    }
  }
  int e = t;
  if (e < NE) {
    int s1 = seg[e];
    if (e == 0) {
      for (int n = 0; n <= s1; ++n) off[n] = 0;
    } else {
      int s0 = seg[e - 1];
      for (int n = s0 + 1; n <= s1; ++n) off[n] = e;
    }
    if (e == NE - 1) {
      for (int n = s1 + 1; n <= NN; ++n) off[n] = NE;
    }
  }
}

// ---------------- k1: per-node edge aggregation; writes Sp as bf16 hi/lo.
__global__ __launch_bounds__(256) void k1_edge_agg(
    const float* __restrict__ contexts, const float* __restrict__ attn,
    const int* __restrict__ off, ushort_t* __restrict__ Sph,
    ushort_t* __restrict__ Spl, float* __restrict__ aprime,
    float* __restrict__ degw) {
  int n = blockIdx.x * 4 + (threadIdx.x >> 6);
  int lane = threadIdx.x & 63;
  if (n >= NN) return;
  int s = off[n];
  int e_end = off[n + 1];
  int deg_i = e_end - s;

  int sub = lane >> 4;
  int fq = lane & 15;
  const float4* ctx4 = (const float4*)contexts;

  float4 S = make_float4(0.f, 0.f, 0.f, 0.f);
  float A = 0.f;
  if (deg_i > 0) {
    int last = e_end - 1;
    for (int e0 = s; e0 < e_end; e0 += 16) {
      float a[4];
      float4 c[4];
#pragma unroll
      for (int u = 0; u < 4; ++u) {
        int eu = e0 + 4 * u + sub;
        a[u] = (eu < e_end) ? attn[eu] : 0.f;
        c[u] = ctx4[(size_t)min(eu, last) * 16 + fq];
      }
#pragma unroll
      for (int u = 0; u < 4; ++u) {
        S.x += a[u] * c[u].x;
        S.y += a[u] * c[u].y;
        S.z += a[u] * c[u].z;
        S.w += a[u] * c[u].w;
        A += a[u];
      }
    }
  }
#pragma unroll
  for (int m = 16; m <= 32; m <<= 1) {
    S.x += __shfl_xor(S.x, m);
    S.y += __shfl_xor(S.y, m);
    S.z += __shfl_xor(S.z, m);
    S.w += __shfl_xor(S.w, m);
    A += __shfl_xor(A, m);
  }
  float deg = (float)deg_i;
  float inv = 1.f / fmaxf(deg, 1.f);
  if (lane < 16) {
    float ox = S.x * inv, oy = S.y * inv, oz = S.z * inv, ow = S.w * inv;
    uint2 hp, lp;
    hp.x = pack_hi(ox, oy);
    hp.y = pack_hi(oz, ow);
    lp.x = pack_lo(ox, oy);
    lp.y = pack_lo(oz, ow);
    *(uint2*)&Sph[(size_t)n * 64 + lane * 4] = hp;
    *(uint2*)&Spl[(size_t)n * 64 + lane * 4] = lp;
  }
  if (lane == 0) { aprime[n] = A * inv; degw[n] = deg; }
}

// ---------------- k234: fused MFMA pipeline, 64-node tile, 4 waves, N-split.
// Weights hi-only, ALL B-fragments held in registers (B1/B2 hoisted to entry,
// B3 issued under GEMM2+transform). K-loops are pure {ds_read A + MFMA}.
// GEMM1: 2-term (input hi/lo x weight-hi). GEMM2/KAN: 1-term.
__global__ __launch_bounds__(256, 3) void k234(
    const float* __restrict__ x,
    const ushort_t* __restrict__ Sph, const ushort_t* __restrict__ Spl,
    const float* __restrict__ aprime, const float* __restrict__ degw,
    const float* __restrict__ bn, const float* __restrict__ bc,
    const float* __restrict__ bu,
    const ushort_t* __restrict__ p1h, const ushort_t* __restrict__ p2h,
    const ushort_t* __restrict__ p3h,
    const float* __restrict__ gridp, float* __restrict__ out) {
  __shared__ __align__(16) unsigned char arena[49152];
  __shared__ float ap[64], degl[64];
  ushort_t* Uh = (ushort_t*)arena;             // [64][128] swizzled
  ushort_t* Ul = (ushort_t*)(arena + 16384);   // [64][128] swizzled
  ushort_t* Th = (ushort_t*)(arena + 32768);   // [64][128] swizzled
  ushort_t* Vh = (ushort_t*)arena;             // [32][392], overlays Uh + part of Ul

  int tid = threadIdx.x;
  int n0 = blockIdx.x * 64;
  int w = tid >> 6, l = tid & 63;
  int lm = l & 15, lk = l >> 4;
  const short8* P1h = (const short8*)p1h;
  const short8* P2h = (const short8*)p2h;
  const short8* P3h = (const short8*)p3h;

  // ---- hoisted B-fragments for GEMM1 + GEMM2 (registers, issued immediately)
  short8 B1[2][4], B2[4];
#pragma unroll
  for (int q2 = 0; q2 < 2; ++q2)
#pragma unroll
    for (int ks = 0; ks < 4; ++ks) B1[q2][ks] = P1h[((2 * w + q2) * 4 + ks) * 64 + l];
#pragma unroll
  for (int ks = 0; ks < 4; ++ks) B2[ks] = P2h[(w * 4 + ks) * 64 + l];

  float g[8];
#pragma unroll
  for (int j = 0; j < 8; ++j) g[j] = gridp[j];
  float r1[7], r2[6];
#pragma unroll
  for (int j = 0; j < 7; ++j) r1[j] = 1.f / (g[j + 1] - g[j]);
#pragma unroll
  for (int j = 0; j < 6; ++j) r2[j] = 1.f / (g[j + 2] - g[j]);
  float buv = bu[w * 16 + lm];

  // ---- stage: x packed on the fly, Sp copied (already hi/lo). Swizzled dest.
  {
    const float4* x4 = (const float4*)x;
    const uint4* Sh4 = (const uint4*)Sph;
    const uint4* Sl4 = (const uint4*)Spl;
    for (int q = tid; q < 1024; q += 256) {
      int row = q >> 4, slot = q & 15;
      int n = n0 + row;
      int idx = (row * 128 + slot * 8) ^ ((row & 7) << 3);
      if (slot < 8) {
        float4 a = make_float4(0.f, 0.f, 0.f, 0.f), b = a;
        if (n < NN) {
          a = x4[(size_t)n * 16 + slot * 2];
          b = x4[(size_t)n * 16 + slot * 2 + 1];
        }
        uint4 hp, lp;
        hp.x = pack_hi(a.x, a.y); hp.y = pack_hi(a.z, a.w);
        hp.z = pack_hi(b.x, b.y); hp.w = pack_hi(b.z, b.w);
        lp.x = pack_lo(a.x, a.y); lp.y = pack_lo(a.z, a.w);
        lp.z = pack_lo(b.x, b.y); lp.w = pack_lo(b.z, b.w);
        *(uint4*)&Uh[idx] = hp;
        *(uint4*)&Ul[idx] = lp;
      } else {
        uint4 vh = make_uint4(0u, 0u, 0u, 0u), vl = vh;
        if (n < NN) {
          vh = Sh4[(size_t)n * 8 + (slot & 7)];
          vl = Sl4[(size_t)n * 8 + (slot & 7)];
        }
        *(uint4*)&Uh[idx] = vh;
        *(uint4*)&Ul[idx] = vl;
      }
    }
  }
  if (tid < 64) {
    int n = n0 + tid;
    ap[tid] = (n < NN) ? aprime[n] : 0.f;
    degl[tid] = (n < NN) ? degw[n] : 1.f;
  }
  __syncthreads();  // A

  int swzA = (lm & 7) << 3;

  // ---- GEMM1 (2-term): ks-outer, A loaded once, both h-tiles from registers.
  f32x4 acc1[2][4];
#pragma unroll
  for (int q2 = 0; q2 < 2; ++q2)
#pragma unroll
    for (int mt = 0; mt < 4; ++mt) acc1[q2][mt] = (f32x4){0.f, 0.f, 0.f, 0.f};
#pragma unroll
  for (int ks = 0; ks < 4; ++ks) {
    short8 ah[4], al[4];
#pragma unroll
    for (int mt = 0; mt < 4; ++mt) {
      int ai = ((mt * 16 + lm) * 128 + ks * 32 + lk * 8) ^ swzA;
      ah[mt] = *(const short8*)&Uh[ai];
      al[mt] = *(const short8*)&Ul[ai];
    }
#pragma unroll
    for (int q2 = 0; q2 < 2; ++q2)
#pragma unroll
      for (int mt = 0; mt < 4; ++mt) {
        acc1[q2][mt] = MFMA(ah[mt], B1[q2][ks], acc1[q2][mt]);
        acc1[q2][mt] = MFMA(al[mt], B1[q2][ks], acc1[q2][mt]);
      }
  }
  // bias + T-write (hi-only)
#pragma unroll
  for (int q2 = 0; q2 < 2; ++q2) {
    int h = (2 * w + q2) * 16 + lm;
    float bnv = bn[h], bcv = bc[h];
#pragma unroll
    for (int mt = 0; mt < 4; ++mt) {
#pragma unroll
      for (int r = 0; r < 4; ++r) {
        int node = mt * 16 + lk * 4 + r;
        float t = acc1[q2][mt][r] + bnv + ap[node] * bcv;
        Th[(node * 128 + h) ^ ((node & 7) << 3)] = hi_u(t);
      }
    }
  }
  __syncthreads();  // B

  // ---- issue KAN B-loads now: latency hides under GEMM2 + transform
  short8 B3[12];
#pragma unroll
  for (int ks = 0; ks < 12; ++ks) B3[ks] = P3h[(w * 12 + ks) * 64 + l];

  // ---- GEMM2 (1-term): wave w -> o-tile w. K=128.
  f32x4 acc2[4];
#pragma unroll
  for (int mt = 0; mt < 4; ++mt) acc2[mt] = (f32x4){0.f, 0.f, 0.f, 0.f};
#pragma unroll
  for (int ks = 0; ks < 4; ++ks) {
#pragma unroll
    for (int mt = 0; mt < 4; ++mt) {
      int ai = ((mt * 16 + lm) * 128 + ks * 32 + lk * 8) ^ swzA;
      short8 ah = *(const short8*)&Th[ai];
      acc2[mt] = MFMA(ah, B2[ks], acc2[mt]);
    }
  }
  // no barrier: Vh overlays Uh/Ul (last read before barrier B); GEMM2 reads Th only

  // ---- two 32-node halves: transform -> Vh (hi-only), KAN GEMM (1-term), store
#pragma unroll
  for (int half = 0; half < 2; ++half) {
#pragma unroll
    for (int ms = 0; ms < 2; ++ms) {
      int mt = half * 2 + ms;
#pragma unroll
      for (int r = 0; r < 4; ++r) {
        float xv = acc2[mt][r] + buv;
        float sil = xv / (1.f + __expf(-xv));
        float b0[7], b1[6], b2[5];
#pragma unroll
        for (int q = 0; q < 7; ++q) b0[q] = (xv >= g[q] && xv < g[q + 1]) ? 1.f : 0.f;
#pragma unroll
        for (int q = 0; q < 6; ++q)
          b1[q] = (xv - g[q]) * r1[q] * b0[q] + (g[q + 2] - xv) * r1[q + 1] * b0[q + 1];
#pragma unroll
        for (int q = 0; q < 5; ++q)
          b2[q] = (xv - g[q]) * r2[q] * b1[q] + (g[q + 3] - xv) * r2[q + 1] * b1[q + 1];
        int ln = ms * 16 + lk * 4 + r;
        int base = ln * 392 + (w * 16 + lm) * 6;
        *(unsigned*)&Vh[base + 0] = pack_hi(sil, b2[0]);
        *(unsigned*)&Vh[base + 2] = pack_hi(b2[1], b2[2]);
        *(unsigned*)&Vh[base + 4] = pack_hi(b2[3], b2[4]);
      }
    }
    __syncthreads();  // V ready

    f32x4 accK[2];
    accK[0] = (f32x4){0.f, 0.f, 0.f, 0.f};
    accK[1] = (f32x4){0.f, 0.f, 0.f, 0.f};
#pragma unroll
    for (int ks = 0; ks < 12; ++ks) {
#pragma unroll
      for (int s = 0; s < 2; ++s) {
        short8 ah = *(const short8*)&Vh[(s * 16 + lm) * 392 + ks * 32 + lk * 8];
        accK[s] = MFMA(ah, B3[ks], accK[s]);
      }
    }
    if (half == 0) __syncthreads();  // V reads done before half1 overwrites

#pragma unroll
    for (int s = 0; s < 2; ++s) {
      int o = w * 16 + lm;
#pragma unroll
      for (int r = 0; r < 4; ++r) {
        int node = half * 32 + s * 16 + lk * 4 + r;
        int n = n0 + node;
        if (n < NN) {
          float val = accK[s][r];
          if (degl[node] <= 0.f) val = x[(size_t)n * 64 + o];
          out[(size_t)n * 64 + o] = val;
        }
      }
    }
  }
}

extern "C" void kernel_launch(void* const* d_in, const int* in_sizes, int n_in,
                              void* d_out, int out_size, void* d_ws, size_t ws_size,
                              hipStream_t stream) {
  const float* x        = (const float*)d_in[0];
  const float* contexts = (const float*)d_in[1];
  const float* attn     = (const float*)d_in[2];
  const int*   seg      = (const int*)d_in[3];
  const float* Wn       = (const float*)d_in[4];
  const float* bn       = (const float*)d_in[5];
  const float* Wc       = (const float*)d_in[6];
  const float* bc       = (const float*)d_in[7];
  const float* Wu       = (const float*)d_in[8];
  const float* bu       = (const float*)d_in[9];
  const float* base_w   = (const float*)d_in[10];
  const float* spline_w = (const float*)d_in[11];
  const float* scaler   = (const float*)d_in[12];
  const float* gridp    = (const float*)d_in[13];
  float* out = (float*)d_out;

  ushort_t* us  = (ushort_t*)d_ws;
  ushort_t* Sph = us;                    // 3,200,000
  ushort_t* Spl = Sph + 3200000;         // 3,200,000
  ushort_t* p1h = Spl + 3200000;         // 16384
  ushort_t* p2h = p1h + 16384;           // 8192
  ushort_t* p3h = p2h + 8192;            // 24576
  float* aprime = (float*)(p3h + 24576); // 50,000
  float* degw   = aprime + 50000;        // 50,000
  int*   off    = (int*)(degw + 50000);  // 50,001

  kA_pack_off<<<3125, 256, 0, stream>>>(Wn, Wc, Wu, base_w, spline_w, scaler, seg,
                                        p1h, p2h, p3h, off);
  k1_edge_agg<<<12500, 256, 0, stream>>>(contexts, attn, off, Sph, Spl, aprime, degw);
  k234<<<782, 256, 0, stream>>>(x, Sph, Spl, aprime, degw, bn, bc, bu,
                                p1h, p2h, p3h, gridp, out);
}

// Round 13
// 67.490 us; speedup vs baseline: 6.6528x; 1.0838x over previous
//
#include <hip/hip_runtime.h>
#include <hip/hip_bf16.h>

#define NN 50000
#define NE 800000

typedef short short8 __attribute__((ext_vector_type(8)));
typedef float f32x4 __attribute__((ext_vector_type(4)));
typedef unsigned short ushort_t;

// ---- truncation-based bf16 hi/lo split helpers ----
static __device__ __forceinline__ unsigned bits(float f) { return __float_as_uint(f); }
static __device__ __forceinline__ float hi_f(float v) {
  return __uint_as_float(bits(v) & 0xFFFF0000u);
}
static __device__ __forceinline__ ushort_t hi_u(float v) { return (ushort_t)(bits(v) >> 16); }
static __device__ __forceinline__ unsigned pack_hi(float v0, float v1) {
  return (bits(v0) >> 16) | (bits(v1) & 0xFFFF0000u);
}
static __device__ __forceinline__ unsigned pack_lo(float v0, float v1) {
  float l0 = v0 - hi_f(v0), l1 = v1 - hi_f(v1);
  return (bits(l0) >> 16) | (bits(l1) & 0xFFFF0000u);
}

#define MFMA(a, b, c) __builtin_amdgcn_mfma_f32_16x16x32_bf16(a, b, c, 0, 0, 0)

// ---------------- kA: weight-pack hi-only (t < 4096) + CSR offsets (all threads).
// B-frag for W[N][K]: P[((nt*KS+ks)*64+l)*8+j] = W[nt*16+(l&15)][ks*32+8*(l>>4)+j]
__global__ __launch_bounds__(256) void kA_pack_off(
    const float* __restrict__ Wn, const float* __restrict__ Wc,
    const float* __restrict__ Wu, const float* __restrict__ base_w,
    const float* __restrict__ spline_w, const float* __restrict__ scaler,
    const int* __restrict__ seg,
    ushort_t* __restrict__ p1h, ushort_t* __restrict__ p2h,
    ushort_t* __restrict__ p3h, int* __restrict__ off) {
  int t = blockIdx.x * 256 + threadIdx.x;
  if (t < 4096) {
    int l = t & 63, lm = l & 15, lk = l >> 4;
    if (t < 2048) {
      int nt = t >> 8, ks = (t >> 6) & 3;
      int h = nt * 16 + lm;
#pragma unroll
      for (int j = 0; j < 8; ++j) {
        int f = ks * 32 + lk * 8 + j;
        float v = (f < 64) ? Wn[h * 64 + f] : Wc[h * 64 + (f - 64)];
        p1h[t * 8 + j] = hi_u(v);
      }
    }
    if (t < 1024) {
      int nt = t >> 8, ks = (t >> 6) & 3;
      int o = nt * 16 + lm;
#pragma unroll
      for (int j = 0; j < 8; ++j) {
        int hh = ks * 32 + lk * 8 + j;
        p2h[t * 8 + j] = hi_u(Wu[o * 128 + hh]);
      }
    }
    if (t < 3072) {
      int nt = t / 768, ks = (t >> 6) % 12;
      int o = nt * 16 + lm;
#pragma unroll
      for (int j = 0; j < 8; ++j) {
        int k = ks * 32 + lk * 8 + j;
        int i = k / 6, c = k % 6;
        float v = (c == 0) ? base_w[o * 64 + i]
                           : spline_w[(o * 64 + i) * 5 + (c - 1)] * scaler[o * 64 + i];
        p3h[t * 8 + j] = hi_u(v);
      }
    }
  }
  int e = t;
  if (e < NE) {
    int s1 = seg[e];
    if (e == 0) {
      for (int n = 0; n <= s1; ++n) off[n] = 0;
    } else {
      int s0 = seg[e - 1];
      for (int n = s0 + 1; n <= s1; ++n) off[n] = e;
    }
    if (e == NE - 1) {
      for (int n = s1 + 1; n <= NN; ++n) off[n] = NE;
    }
  }
}

// ---------------- k1234: FULLY fused pipeline. 64-node tile, 512 threads (8 waves, 2M x 4N).
// Phase E: edge-agg (wave w -> 8 nodes) writes Sp part of U directly (bf16 hi/lo).
// GEMM1: wave(wm,wn) -> m-tiles {2wm,2wm+1} x h-tiles {2wn,2wn+1}, input hi/lo x weight-hi.
// GEMM2: wave -> m-pair wm x o-tile wn (upd in regs). KAN: transform by owning waves,
// GEMM o-tile wn x row-tile wm. All weights in registers.
__global__ __launch_bounds__(512, 4) void k1234(
    const float* __restrict__ x,
    const float* __restrict__ contexts, const float* __restrict__ attn,
    const int* __restrict__ off,
    const float* __restrict__ bn, const float* __restrict__ bc,
    const float* __restrict__ bu,
    const ushort_t* __restrict__ p1h, const ushort_t* __restrict__ p2h,
    const ushort_t* __restrict__ p3h,
    const float* __restrict__ gridp, float* __restrict__ out) {
  __shared__ __align__(16) unsigned char arena[49152];
  __shared__ float ap[64], degl[64];
  ushort_t* Uh = (ushort_t*)arena;             // [64][128] swizzled
  ushort_t* Ul = (ushort_t*)(arena + 16384);   // [64][128] swizzled
  ushort_t* Th = (ushort_t*)(arena + 32768);   // [64][128] swizzled
  ushort_t* Vh = (ushort_t*)arena;             // [32][392], overlays Uh + part of Ul

  int tid = threadIdx.x;
  int n0 = blockIdx.x * 64;
  int w = tid >> 6, l = tid & 63;
  int wm = w >> 2, wn = w & 3;
  int lm = l & 15, lk = l >> 4;
  const short8* P1h = (const short8*)p1h;
  const short8* P2h = (const short8*)p2h;
  const short8* P3h = (const short8*)p3h;

  // ---- phase X: stage x (cols 0..63) as bf16 hi/lo, swizzled. One pass (512 thr).
  {
    const float4* x4 = (const float4*)x;
    int row = tid >> 3, slot = tid & 7;
    int n = n0 + row;
    float4 a = make_float4(0.f, 0.f, 0.f, 0.f), b = a;
    if (n < NN) {
      a = x4[(size_t)n * 16 + slot * 2];
      b = x4[(size_t)n * 16 + slot * 2 + 1];
    }
    uint4 hp, lp;
    hp.x = pack_hi(a.x, a.y); hp.y = pack_hi(a.z, a.w);
    hp.z = pack_hi(b.x, b.y); hp.w = pack_hi(b.z, b.w);
    lp.x = pack_lo(a.x, a.y); lp.y = pack_lo(a.z, a.w);
    lp.z = pack_lo(b.x, b.y); lp.w = pack_lo(b.z, b.w);
    int idx = (row * 128 + slot * 8) ^ ((row & 7) << 3);
    *(uint4*)&Uh[idx] = hp;
    *(uint4*)&Ul[idx] = lp;
  }

  // ---- phase E: edge aggregation, wave w -> nodes [n0+w*8, n0+w*8+8).
  {
    int nb = n0 + w * 8;
    int offv = 0;
    if (l < 9) offv = off[min(nb + l, NN)];
    int sub = l >> 4, fq = l & 15;
    const float4* ctx4 = (const float4*)contexts;
#pragma unroll 1
    for (int i = 0; i < 8; ++i) {
      int s = __shfl(offv, i);
      int e_end = __shfl(offv, i + 1);
      int deg_i = e_end - s;
      float4 S = make_float4(0.f, 0.f, 0.f, 0.f);
      float A = 0.f;
      if (deg_i > 0) {
        int last = e_end - 1;
        for (int e0 = s; e0 < e_end; e0 += 16) {
          float a[4];
          float4 c[4];
#pragma unroll
          for (int u = 0; u < 4; ++u) {
            int eu = e0 + 4 * u + sub;
            a[u] = (eu < e_end) ? attn[eu] : 0.f;
            c[u] = ctx4[(size_t)min(eu, last) * 16 + fq];
          }
#pragma unroll
          for (int u = 0; u < 4; ++u) {
            S.x += a[u] * c[u].x;
            S.y += a[u] * c[u].y;
            S.z += a[u] * c[u].z;
            S.w += a[u] * c[u].w;
            A += a[u];
          }
        }
      }
#pragma unroll
      for (int m = 16; m <= 32; m <<= 1) {
        S.x += __shfl_xor(S.x, m);
        S.y += __shfl_xor(S.y, m);
        S.z += __shfl_xor(S.z, m);
        S.w += __shfl_xor(S.w, m);
        A += __shfl_xor(A, m);
      }
      float deg = (float)deg_i;
      float inv = 1.f / fmaxf(deg, 1.f);
      int row = w * 8 + i;
      if (l < 16) {
        float ox = S.x * inv, oy = S.y * inv, oz = S.z * inv, ow = S.w * inv;
        uint2 hp, lp;
        hp.x = pack_hi(ox, oy);
        hp.y = pack_hi(oz, ow);
        lp.x = pack_lo(ox, oy);
        lp.y = pack_lo(oz, ow);
        int idx = (row * 128 + 64 + l * 4) ^ ((row & 7) << 3);
        *(uint2*)&Uh[idx] = hp;
        *(uint2*)&Ul[idx] = lp;
      }
      if (l == 0) { ap[row] = A * inv; degl[row] = deg; }
    }
  }

  // ---- hoist GEMM1/GEMM2 B-fragments (latency overlaps barrier)
  short8 B1[2][4], B2[4];
#pragma unroll
  for (int q = 0; q < 2; ++q)
#pragma unroll
    for (int ks = 0; ks < 4; ++ks) B1[q][ks] = P1h[((2 * wn + q) * 4 + ks) * 64 + l];
#pragma unroll
  for (int ks = 0; ks < 4; ++ks) B2[ks] = P2h[(wn * 4 + ks) * 64 + l];

  __syncthreads();  // A: U tile complete

  int swzA = (lm & 7) << 3;

  // ---- GEMM1 (2-term): m-tiles {2wm, 2wm+1} x h-tiles {2wn, 2wn+1}. K=128.
  f32x4 acc1[2][2];  // [q=h-tile][ms=m-tile]
#pragma unroll
  for (int q = 0; q < 2; ++q)
#pragma unroll
    for (int ms = 0; ms < 2; ++ms) acc1[q][ms] = (f32x4){0.f, 0.f, 0.f, 0.f};
#pragma unroll
  for (int ks = 0; ks < 4; ++ks) {
    short8 ah[2], al[2];
#pragma unroll
    for (int ms = 0; ms < 2; ++ms) {
      int ai = (((2 * wm + ms) * 16 + lm) * 128 + ks * 32 + lk * 8) ^ swzA;
      ah[ms] = *(const short8*)&Uh[ai];
      al[ms] = *(const short8*)&Ul[ai];
    }
#pragma unroll
    for (int q = 0; q < 2; ++q)
#pragma unroll
      for (int ms = 0; ms < 2; ++ms) {
        acc1[q][ms] = MFMA(ah[ms], B1[q][ks], acc1[q][ms]);
        acc1[q][ms] = MFMA(al[ms], B1[q][ks], acc1[q][ms]);
      }
  }
  // bias + T-write (hi-only)
#pragma unroll
  for (int q = 0; q < 2; ++q) {
    int h = (2 * wn + q) * 16 + lm;
    float bnv = bn[h], bcv = bc[h];
#pragma unroll
    for (int ms = 0; ms < 2; ++ms) {
#pragma unroll
      for (int r = 0; r < 4; ++r) {
        int node = (2 * wm + ms) * 16 + lk * 4 + r;
        float t = acc1[q][ms][r] + bnv + ap[node] * bcv;
        Th[(node * 128 + h) ^ ((node & 7) << 3)] = hi_u(t);
      }
    }
  }
  __syncthreads();  // B: GEMM1 reads done, T ready

  // ---- issue KAN B-loads + spline constants now (hide under GEMM2)
  short8 B3[12];
#pragma unroll
  for (int ks = 0; ks < 12; ++ks) B3[ks] = P3h[(wn * 12 + ks) * 64 + l];
  float g[8];
#pragma unroll
  for (int j = 0; j < 8; ++j) g[j] = gridp[j];
  float r1[7], r2[6];
#pragma unroll
  for (int j = 0; j < 7; ++j) r1[j] = 1.f / (g[j + 1] - g[j]);
#pragma unroll
  for (int j = 0; j < 6; ++j) r2[j] = 1.f / (g[j + 2] - g[j]);
  float buv = bu[wn * 16 + lm];

  // ---- GEMM2 (1-term): m-tiles {2wm, 2wm+1} x o-tile wn. K=128.
  f32x4 acc2[2];
  acc2[0] = (f32x4){0.f, 0.f, 0.f, 0.f};
  acc2[1] = (f32x4){0.f, 0.f, 0.f, 0.f};
#pragma unroll
  for (int ks = 0; ks < 4; ++ks) {
#pragma unroll
    for (int ms = 0; ms < 2; ++ms) {
      int ai = (((2 * wm + ms) * 16 + lm) * 128 + ks * 32 + lk * 8) ^ swzA;
      short8 ah = *(const short8*)&Th[ai];
      acc2[ms] = MFMA(ah, B2[ks], acc2[ms]);
    }
  }
  // (no barrier: Vh overlays Uh/Ul which are dead after barrier B; GEMM2 reads Th only)

  // ---- two 32-node halves: transform (owning waves) -> Vh, KAN GEMM, store
#pragma unroll
  for (int half = 0; half < 2; ++half) {
    if (wm == half) {
#pragma unroll
      for (int ms = 0; ms < 2; ++ms) {
#pragma unroll
        for (int r = 0; r < 4; ++r) {
          float xv = acc2[ms][r] + buv;
          float sil = xv / (1.f + __expf(-xv));
          float b0[7], b1[6], b2[5];
#pragma unroll
          for (int q = 0; q < 7; ++q) b0[q] = (xv >= g[q] && xv < g[q + 1]) ? 1.f : 0.f;
#pragma unroll
          for (int q = 0; q < 6; ++q)
            b1[q] = (xv - g[q]) * r1[q] * b0[q] + (g[q + 2] - xv) * r1[q + 1] * b0[q + 1];
#pragma unroll
          for (int q = 0; q < 5; ++q)
            b2[q] = (xv - g[q]) * r2[q] * b1[q] + (g[q + 3] - xv) * r2[q + 1] * b1[q + 1];
          int ln = ms * 16 + lk * 4 + r;
          int base = ln * 392 + (wn * 16 + lm) * 6;
          *(unsigned*)&Vh[base + 0] = pack_hi(sil, b2[0]);
          *(unsigned*)&Vh[base + 2] = pack_hi(b2[1], b2[2]);
          *(unsigned*)&Vh[base + 4] = pack_hi(b2[3], b2[4]);
        }
      }
    }
    __syncthreads();  // V ready

    // KAN GEMM (1-term): o-tile wn, row-tile wm within this half. K=384.
    f32x4 accK = (f32x4){0.f, 0.f, 0.f, 0.f};
#pragma unroll
    for (int ks = 0; ks < 12; ++ks) {
      short8 ah = *(const short8*)&Vh[(wm * 16 + lm) * 392 + ks * 32 + lk * 8];
      accK = MFMA(ah, B3[ks], accK);
    }
    if (half == 0) __syncthreads();  // V reads done before half1 overwrites

    int o = wn * 16 + lm;
#pragma unroll
    for (int r = 0; r < 4; ++r) {
      int node = half * 32 + wm * 16 + lk * 4 + r;
      int n = n0 + node;
      if (n < NN) {
        float val = accK[r];
        if (degl[node] <= 0.f) val = x[(size_t)n * 64 + o];
        out[(size_t)n * 64 + o] = val;
      }
    }
  }
}

extern "C" void kernel_launch(void* const* d_in, const int* in_sizes, int n_in,
                              void* d_out, int out_size, void* d_ws, size_t ws_size,
                              hipStream_t stream) {
  const float* x        = (const float*)d_in[0];
  const float* contexts = (const float*)d_in[1];
  const float* attn     = (const float*)d_in[2];
  const int*   seg      = (const int*)d_in[3];
  const float* Wn       = (const float*)d_in[4];
  const float* bn       = (const float*)d_in[5];
  const float* Wc       = (const float*)d_in[6];
  const float* bc       = (const float*)d_in[7];
  const float* Wu       = (const float*)d_in[8];
  const float* bu       = (const float*)d_in[9];
  const float* base_w   = (const float*)d_in[10];
  const float* spline_w = (const float*)d_in[11];
  const float* scaler   = (const float*)d_in[12];
  const float* gridp    = (const float*)d_in[13];
  float* out = (float*)d_out;

  ushort_t* us  = (ushort_t*)d_ws;
  ushort_t* p1h = us;                    // 16384
  ushort_t* p2h = p1h + 16384;           // 8192
  ushort_t* p3h = p2h + 8192;            // 24576
  int*   off    = (int*)(p3h + 24576);   // 50,001

  kA_pack_off<<<3125, 256, 0, stream>>>(Wn, Wc, Wu, base_w, spline_w, scaler, seg,
                                        p1h, p2h, p3h, off);
  k1234<<<782, 512, 0, stream>>>(x, contexts, attn, off, bn, bc, bu,
                                 p1h, p2h, p3h, gridp, out);
}